// Round 3
// baseline (9443.439 us; speedup 1.0000x reference)
//
#include <hip/hip_runtime.h>
#include <math.h>

#define N_NODES 50000
#define N_EDGES 800000
#define M_HID   128
#define P_FEAT  256
#define C_OUT   40
#define PWR_ITERS 50
#define FP_ITERS  30
#define KAPPA 0.9f

// ---------------- power iteration ----------------

__global__ void fill_pow(float* buf0, float* buf1, float* ss, int n, float val) {
    int i = blockIdx.x * blockDim.x + threadIdx.x;
    if (i < n) { buf0[i] = val; buf1[i] = 0.f; }
    if (blockIdx.x == 0 && threadIdx.x < 64) ss[threadIdx.x] = (threadIdx.x == 0) ? 1.f : 0.f;
}

__global__ void scatter_pow(const int* __restrict__ src, const int* __restrict__ dst,
                            const float* __restrict__ w, const float* __restrict__ vin,
                            const float* __restrict__ norm2, float* vout, int E) {
    int e = blockIdx.x * blockDim.x + threadIdx.x;
    if (e >= E) return;
    float inv = 1.f / (sqrtf(*norm2) + 1e-12f);
    atomicAdd(&vout[src[e]], w[e] * vin[dst[e]] * inv);
}

__global__ void reduce_zero(const float* __restrict__ av, float* zbuf, int n, float* out) {
    float s = 0.f;
    for (int i = blockIdx.x * blockDim.x + threadIdx.x; i < n; i += gridDim.x * blockDim.x) {
        float x = av[i]; s += x * x;
        zbuf[i] = 0.f;
    }
    for (int o = 32; o > 0; o >>= 1) s += __shfl_down(s, o, 64);
    __shared__ float ls[16];
    int lane = threadIdx.x & 63, wid = threadIdx.x >> 6;
    if (lane == 0) ls[wid] = s;
    __syncthreads();
    if (threadIdx.x == 0) {
        float t = 0.f; int nw = blockDim.x >> 6;
        for (int i = 0; i < nw; ++i) t += ls[i];
        atomicAdd(out, t);
    }
}

// ---------------- L1-ball row projection of W ----------------

__global__ __launch_bounds__(128) void project_w(const float* __restrict__ W,
                                                 const float* __restrict__ rho2,
                                                 float* Wp, float* WpT) {
    __shared__ float sa[128];
    __shared__ float ssort[128];
    __shared__ float sc[128];
    __shared__ int cnt2[2];
    int r = blockIdx.x, t = threadIdx.x;
    float radius = KAPPA / sqrtf(*rho2);
    float w0 = W[r * 128 + t];
    float a = fabsf(w0);
    sa[t] = a;
    __syncthreads();
    int rank = 0;
    #pragma unroll 8
    for (int j = 0; j < 128; ++j) {
        float aj = sa[j];
        rank += (aj > a) || (aj == a && j < t);
    }
    ssort[rank] = a;
    __syncthreads();
    sc[t] = ssort[t];
    __syncthreads();
    for (int off = 1; off < 128; off <<= 1) {
        float add = (t >= off) ? sc[t - off] : 0.f;
        __syncthreads();
        sc[t] += add;
        __syncthreads();
    }
    bool flag = ssort[t] * (float)(t + 1) > sc[t] - radius;
    unsigned long long b = __ballot(flag);
    if ((t & 63) == 0) cnt2[t >> 6] = __popcll(b);
    __syncthreads();
    int rho = cnt2[0] + cnt2[1];
    float total = sc[127];
    bool needs = total > radius;
    float theta = (sc[rho - 1] - radius) / (float)rho;
    float o;
    if (needs) {
        float am = a - theta;
        o = (am > 0.f) ? ((w0 > 0.f) ? am : -am) : 0.f;
    } else o = w0;
    Wp[r * 128 + t] = o;
    WpT[t * 128 + r] = o;
}

// ---------------- CSR build (by dst) ----------------

__global__ void count_deg(const int* __restrict__ dst, int* deg, int E) {
    int e = blockIdx.x * blockDim.x + threadIdx.x;
    if (e < E) atomicAdd(&deg[dst[e]], 1);
}

__global__ __launch_bounds__(1024) void scan_offsets(const int* __restrict__ deg,
                                                     int* offsets, int* cursor, int n) {
    __shared__ int partial[1024];
    int tid = threadIdx.x;
    int chunk = (n + 1023) / 1024;
    int lo = tid * chunk;
    int hi = lo + chunk; if (hi > n) hi = n; if (lo > n) lo = n;
    int s = 0;
    for (int i = lo; i < hi; ++i) s += deg[i];
    partial[tid] = s;
    __syncthreads();
    for (int od = 1; od < 1024; od <<= 1) {
        int val = 0;
        if (tid >= od) val = partial[tid - od];
        __syncthreads();
        if (tid >= od) partial[tid] += val;
        __syncthreads();
    }
    int base = (tid == 0) ? 0 : partial[tid - 1];
    for (int i = lo; i < hi; ++i) {
        offsets[i] = base; cursor[i] = base;
        base += deg[i];
    }
    if (tid == 1023) offsets[n] = partial[1023];
}

__global__ void fill_csr(const int* __restrict__ src, const int* __restrict__ dst,
                         const float* __restrict__ w, int* cursor,
                         int* csr_src, float* csr_w, int E) {
    int e = blockIdx.x * blockDim.x + threadIdx.x;
    if (e < E) {
        int p = atomicAdd(&cursor[dst[e]], 1);
        csr_src[p] = src[e];
        csr_w[p] = w[e];
    }
}

// ---------------- small transposes ----------------

__global__ void transpose_om(const float* __restrict__ Om, float* OmT) {
    int idx = blockIdx.x * blockDim.x + threadIdx.x;
    if (idx < 128 * 256) {
        int t = idx / 256, k = idx % 256;
        OmT[k * 128 + t] = Om[idx];
    }
}

__global__ void transpose_x0(const float* __restrict__ X0, float* Xt, int n) {
    __shared__ float tile[32][33];
    int jb = blockIdx.x * 32, tb = blockIdx.y * 32;
    int tx = threadIdx.x, ty = threadIdx.y;
    for (int r = 0; r < 32; r += 8) {
        int t = tb + ty + r, j = jb + tx;
        tile[ty + r][tx] = (j < n) ? X0[(size_t)t * n + j] : 0.f;
    }
    __syncthreads();
    for (int r = 0; r < 32; r += 8) {
        int j = jb + ty + r, t = tb + tx;
        if (j < n) Xt[(size_t)j * 128 + t] = tile[tx][ty + r];
    }
}

// ---------------- one-shot dense GEMM: Ut = F^T @ OmT ----------------

__global__ __launch_bounds__(256) void gemm_u(const float* __restrict__ F,
                                              const float* __restrict__ OmT,
                                              float* __restrict__ C, int n) {
    __shared__ float Fs[16][129];
    __shared__ float Bs[16][129];
    int j0 = blockIdx.x * 128;
    int tid = threadIdx.x;
    int tj = tid >> 4, tg = tid & 15;
    float acc[8][8] = {};
    for (int k0 = 0; k0 < 256; k0 += 16) {
        for (int r = 0; r < 8; ++r) {
            int idx = r * 256 + tid;
            int kk = idx >> 7, jj = idx & 127;
            int j = j0 + jj;
            Fs[kk][jj] = (j < n) ? F[(size_t)(k0 + kk) * n + j] : 0.f;
            Bs[kk][jj] = OmT[(k0 + kk) * 128 + jj];
        }
        __syncthreads();
        for (int kk = 0; kk < 16; ++kk) {
            float a[8], b[8];
            #pragma unroll
            for (int u = 0; u < 8; ++u) a[u] = Fs[kk][tj + 16 * u];
            #pragma unroll
            for (int u = 0; u < 8; ++u) b[u] = Bs[kk][tg + 16 * u];
            #pragma unroll
            for (int x = 0; x < 8; ++x)
                #pragma unroll
                for (int y = 0; y < 8; ++y)
                    acc[x][y] += a[x] * b[y];
        }
        __syncthreads();
    }
    for (int x = 0; x < 8; ++x) {
        int j = j0 + tj + 16 * x;
        if (j < n)
            for (int y = 0; y < 8; ++y)
                C[(size_t)j * 128 + tg + 16 * y] = acc[x][y];
    }
}

// ---------------- standalone spmm (for b = U @ A) ----------------

__global__ __launch_bounds__(256) void spmm_csr(const int* __restrict__ offsets,
                                                const int* __restrict__ csr_src,
                                                const float* __restrict__ csr_w,
                                                const float* __restrict__ Xin,
                                                float* __restrict__ Yout, int n) {
    int j = blockIdx.x * 4 + (threadIdx.x >> 6);
    if (j >= n) return;
    int lane = threadIdx.x & 63;
    int lo = offsets[j], hi = offsets[j + 1];
    const float2* __restrict__ X2 = (const float2*)Xin;
    float2 acc = {0.f, 0.f};
    for (int e = lo; e < hi; ++e) {
        int s = csr_src[e];
        float w = csr_w[e];
        float2 x = X2[(size_t)s * 64 + lane];
        acc.x += w * x.x;
        acc.y += w * x.y;
    }
    ((float2*)Yout)[(size_t)j * 64 + lane] = acc;
}

// ---------------- fused fixed-point step: Xout = relu(Wp @ (Xin A) + b) ----------------
// 64 nodes per block. Phase 1: gather (Xin A) rows into LDS.
// Phase 2: register-tiled GEMM vs WpT, + bias + relu, write.

__global__ __launch_bounds__(256) void fused_iter(const int* __restrict__ offsets,
                                                  const int* __restrict__ csr_src,
                                                  const float* __restrict__ csr_w,
                                                  const float* __restrict__ Xin,
                                                  const float* __restrict__ WpT,
                                                  const float* __restrict__ bt,
                                                  float* __restrict__ Xout, int n) {
    __shared__ float Ys[64][132];
    __shared__ float Bs[16][129];
    int tid = threadIdx.x;
    int jb = blockIdx.x * 64;
    int wid = tid >> 6, lane = tid & 63;
    const float2* __restrict__ X2 = (const float2*)Xin;

    // ---- gather phase: wave w handles nodes [wid*16, wid*16+16) ----
    for (int i = 0; i < 16; ++i) {
        int row = wid * 16 + i;
        int j = jb + row;
        float2 acc = {0.f, 0.f};
        if (j < n) {
            int lo = offsets[j], hi = offsets[j + 1];
            #pragma unroll 2
            for (int e = lo; e < hi; ++e) {
                int s = csr_src[e];
                float w = csr_w[e];
                float2 x = X2[(size_t)s * 64 + lane];
                acc.x += w * x.x;
                acc.y += w * x.y;
            }
        }
        Ys[row][2 * lane]     = acc.x;
        Ys[row][2 * lane + 1] = acc.y;
    }
    __syncthreads();

    // ---- GEMM phase: (64 x 128) @ (128 x 128) ----
    int tj = tid >> 4, tg = tid & 15;   // 16 x 16 thread grid
    float acc[4][8] = {};
    for (int k0 = 0; k0 < 128; k0 += 16) {
        #pragma unroll
        for (int r = 0; r < 8; ++r) {
            int idx = r * 256 + tid;
            int kk = idx >> 7, tt = idx & 127;
            Bs[kk][tt] = WpT[(k0 + kk) * 128 + tt];
        }
        __syncthreads();
        #pragma unroll
        for (int kk = 0; kk < 16; ++kk) {
            float a[4], b[8];
            #pragma unroll
            for (int x = 0; x < 4; ++x) a[x] = Ys[tj + 16 * x][k0 + kk];
            #pragma unroll
            for (int y = 0; y < 8; ++y) b[y] = Bs[kk][tg + 16 * y];
            #pragma unroll
            for (int x = 0; x < 4; ++x)
                #pragma unroll
                for (int y = 0; y < 8; ++y)
                    acc[x][y] += a[x] * b[y];
        }
        __syncthreads();
    }
    #pragma unroll
    for (int x = 0; x < 4; ++x) {
        int j = jb + tj + 16 * x;
        if (j < n) {
            #pragma unroll
            for (int y = 0; y < 8; ++y) {
                int c = tg + 16 * y;
                float v = acc[x][y] + bt[(size_t)j * 128 + c];
                Xout[(size_t)j * 128 + c] = (v > 0.f) ? v : 0.f;
            }
        }
    }
}

// ---------------- final: normalize rows + H @ Vw^T ----------------
// 64 nodes / block; 4-lane group per node holds the row in registers.

__global__ __launch_bounds__(256) void final_out(const float* __restrict__ Xt,
                                                 const float* __restrict__ Vw,
                                                 float* __restrict__ out, int n) {
    __shared__ float Vs[40][132];   // swizzled: [c][ (k>>5)*33 + (k&31) ]
    int tid = threadIdx.x;
    int jb = blockIdx.x * 64;
    for (int i = tid; i < 40 * 128; i += 256) {
        int c = i >> 7, k = i & 127;
        Vs[c][(k >> 5) * 33 + (k & 31)] = Vw[i];
    }
    int g = tid >> 2, q = tid & 3;
    int j = jb + g;
    float4 xv[8];
    float ss = 0.f;
    if (j < n) {
        const float4* X4 = (const float4*)(Xt + (size_t)j * 128 + q * 32);
        #pragma unroll
        for (int u = 0; u < 8; ++u) {
            xv[u] = X4[u];
            ss += xv[u].x * xv[u].x + xv[u].y * xv[u].y
                + xv[u].z * xv[u].z + xv[u].w * xv[u].w;
        }
    } else {
        #pragma unroll
        for (int u = 0; u < 8; ++u) xv[u] = make_float4(0.f, 0.f, 0.f, 0.f);
    }
    ss += __shfl_xor(ss, 1, 64);
    ss += __shfl_xor(ss, 2, 64);
    float inv = 1.f / fmaxf(sqrtf(ss), 1e-12f);
    #pragma unroll
    for (int u = 0; u < 8; ++u) {
        xv[u].x *= inv; xv[u].y *= inv; xv[u].z *= inv; xv[u].w *= inv;
    }
    __syncthreads();
    // partial dots: this thread covers k in [q*32, q*32+32)
    float pacc[10];
    #pragma unroll
    for (int cc = 0; cc < 10; ++cc) pacc[cc] = 0.f;
    for (int cc = 0; cc < 10; ++cc) {
        // c assigned round-robin: this thread reduces ALL c, then q==c%4 writes
    }
    // compute per-c partials for all 40 c, reduce over the 4 lanes per group
    // c-loop outer; each thread accumulates its 32-k slice
    #pragma unroll 1
    for (int c = 0; c < 40; ++c) {
        const float* vrow = &Vs[c][q * 33];
        float acc = 0.f;
        #pragma unroll
        for (int u = 0; u < 8; ++u) {
            acc += xv[u].x * vrow[4 * u]     + xv[u].y * vrow[4 * u + 1]
                 + xv[u].z * vrow[4 * u + 2] + xv[u].w * vrow[4 * u + 3];
        }
        acc += __shfl_xor(acc, 1, 64);
        acc += __shfl_xor(acc, 2, 64);
        if ((c & 3) == q) pacc[c >> 2] = acc;
    }
    if (j < n) {
        #pragma unroll
        for (int cc = 0; cc < 10; ++cc) {
            int c = cc * 4 + q;
            out[(size_t)j * 40 + c] = pacc[cc];
        }
    }
}

// ---------------- launch ----------------

extern "C" void kernel_launch(void* const* d_in, const int* in_sizes, int n_in,
                              void* d_out, int out_size, void* d_ws, size_t ws_size,
                              hipStream_t stream) {
    const float* F    = (const float*)d_in[0];   // (256, 50000)
    const float* W    = (const float*)d_in[1];   // (128, 128)
    const float* Om   = (const float*)d_in[2];   // (128, 256)
    const float* Vw   = (const float*)d_in[3];   // (40, 128)
    const float* X0   = (const float*)d_in[4];   // (128, 50000)
    const float* ew   = (const float*)d_in[5];   // (E,)
    const int*   esrc = (const int*)d_in[6];
    const int*   edst = (const int*)d_in[7];
    float* out = (float*)d_out;
    (void)in_sizes; (void)n_in; (void)out_size; (void)ws_size;

    char* ws = (char*)d_ws;
    size_t off = 0;
    auto alloc = [&](size_t bytes) -> void* {
        void* p = ws + off;
        off = (off + bytes + 255) & ~(size_t)255;
        return p;
    };
    float* buf0    = (float*)alloc((size_t)N_NODES * 4);
    float* buf1    = (float*)alloc((size_t)N_NODES * 4);
    float* ss      = (float*)alloc(64 * 4);
    int*   deg     = (int*)  alloc((size_t)(N_NODES + 1) * 4);
    int*   offs    = (int*)  alloc((size_t)(N_NODES + 1) * 4);
    int*   cursor  = (int*)  alloc((size_t)N_NODES * 4);
    int*   csr_src = (int*)  alloc((size_t)N_EDGES * 4);
    float* csr_w   = (float*)alloc((size_t)N_EDGES * 4);
    float* Wp      = (float*)alloc(128 * 128 * 4);
    float* WpT     = (float*)alloc(128 * 128 * 4);
    float* OmT     = (float*)alloc(256 * 128 * 4);
    float* bt      = (float*)alloc((size_t)N_NODES * 128 * 4);
    float* Ut      = (float*)alloc((size_t)N_NODES * 128 * 4);
    float* Xa      = (float*)alloc((size_t)N_NODES * 128 * 4);
    float* Xb      = (float*)alloc((size_t)N_NODES * 128 * 4);

    hipMemsetAsync(deg, 0, (size_t)(N_NODES + 1) * 4, stream);

    // ---- power iteration (2 kernels / iter) ----
    float* bufs[2] = {buf0, buf1};
    fill_pow<<<(N_NODES + 255) / 256, 256, 0, stream>>>(
        buf0, buf1, ss, N_NODES, 1.f / sqrtf((float)N_NODES));
    for (int it = 0; it < PWR_ITERS; ++it) {
        scatter_pow<<<(N_EDGES + 255) / 256, 256, 0, stream>>>(
            esrc, edst, ew, bufs[it & 1], ss + it, bufs[(it + 1) & 1], N_EDGES);
        reduce_zero<<<128, 256, 0, stream>>>(bufs[(it + 1) & 1], bufs[it & 1],
                                             N_NODES, ss + it + 1);
    }
    scatter_pow<<<(N_EDGES + 255) / 256, 256, 0, stream>>>(
        esrc, edst, ew, bufs[0], ss + PWR_ITERS, bufs[1], N_EDGES);
    reduce_zero<<<128, 256, 0, stream>>>(bufs[1], bufs[0], N_NODES, ss + PWR_ITERS + 1);

    // ---- project W ----
    project_w<<<128, 128, 0, stream>>>(W, ss + PWR_ITERS + 1, Wp, WpT);

    // ---- CSR by dst ----
    count_deg<<<(N_EDGES + 255) / 256, 256, 0, stream>>>(edst, deg, N_EDGES);
    scan_offsets<<<1, 1024, 0, stream>>>(deg, offs, cursor, N_NODES);
    fill_csr<<<(N_EDGES + 255) / 256, 256, 0, stream>>>(esrc, edst, ew, cursor,
                                                        csr_src, csr_w, N_EDGES);

    // ---- b = (Omega_1 @ U) @ A ----
    transpose_om<<<(128 * 256 + 255) / 256, 256, 0, stream>>>(Om, OmT);
    gemm_u<<<(N_NODES + 127) / 128, 256, 0, stream>>>(F, OmT, Ut, N_NODES);
    spmm_csr<<<(N_NODES + 3) / 4, 256, 0, stream>>>(offs, csr_src, csr_w, Ut, bt, N_NODES);

    // ---- fixed point (fused) ----
    transpose_x0<<<dim3((N_NODES + 31) / 32, 4), dim3(32, 8), 0, stream>>>(X0, Xa, N_NODES);
    float* xb2[2] = {Xa, Xb};
    for (int it = 0; it < FP_ITERS; ++it) {
        fused_iter<<<(N_NODES + 63) / 64, 256, 0, stream>>>(
            offs, csr_src, csr_w, xb2[it & 1], WpT, bt, xb2[(it + 1) & 1], N_NODES);
    }

    // ---- output ----
    final_out<<<(N_NODES + 63) / 64, 256, 0, stream>>>(xb2[FP_ITERS & 1], Vw, out, N_NODES);
}

// Round 4
// 4105.392 us; speedup vs baseline: 2.3003x; 2.3003x over previous
//
#include <hip/hip_runtime.h>
#include <math.h>

#define N_NODES 50000
#define N_EDGES 800000
#define M_HID   128
#define P_FEAT  256
#define C_OUT   40
#define PWR_ITERS 50
#define FP_ITERS  30
#define KAPPA 0.9f

// ---------------- init ----------------

__global__ void fill_pow(float* buf0, float* ss, int n, float val) {
    int i = blockIdx.x * blockDim.x + threadIdx.x;
    if (i < n) buf0[i] = val;
    if (blockIdx.x == 0 && threadIdx.x < 64) ss[threadIdx.x] = (threadIdx.x == 0) ? 1.f : 0.f;
}

// ---------------- power iteration: gather matvec + fused norm ----------------
// av[i] = (1/(|vin|+eps)) * sum_{e in src-CSR[i]} w_e * vin[dst_e]; n2out += av[i]^2

__global__ __launch_bounds__(256) void matvec_norm(const int* __restrict__ offs,
                                                   const int* __restrict__ cdst,
                                                   const float* __restrict__ cw,
                                                   const float* __restrict__ vin,
                                                   const float* __restrict__ n2in,
                                                   float* __restrict__ vout,
                                                   float* n2out, int n) {
    int i = blockIdx.x * blockDim.x + threadIdx.x;
    float inv = 1.f / (sqrtf(*n2in) + 1e-12f);
    float a = 0.f;
    if (i < n) {
        int lo = offs[i], hi = offs[i + 1];
        int e = lo;
        for (; e + 4 <= hi; e += 4) {
            int d0 = cdst[e], d1 = cdst[e + 1], d2 = cdst[e + 2], d3 = cdst[e + 3];
            float w0 = cw[e], w1 = cw[e + 1], w2 = cw[e + 2], w3 = cw[e + 3];
            a += w0 * vin[d0] + w1 * vin[d1] + w2 * vin[d2] + w3 * vin[d3];
        }
        for (; e < hi; ++e) a += cw[e] * vin[cdst[e]];
        a *= inv;
        vout[i] = a;
    }
    float s = a * a;
    for (int o = 32; o > 0; o >>= 1) s += __shfl_down(s, o, 64);
    __shared__ float ls[4];
    int lane = threadIdx.x & 63, wid = threadIdx.x >> 6;
    if (lane == 0) ls[wid] = s;
    __syncthreads();
    if (threadIdx.x == 0) {
        atomicAdd(n2out, ls[0] + ls[1] + ls[2] + ls[3]);
    }
}

// ---------------- L1-ball row projection of W ----------------

__global__ __launch_bounds__(128) void project_w(const float* __restrict__ W,
                                                 const float* __restrict__ rho2,
                                                 float* Wp, float* WpT) {
    __shared__ float sa[128];
    __shared__ float ssort[128];
    __shared__ float sc[128];
    __shared__ int cnt2[2];
    int r = blockIdx.x, t = threadIdx.x;
    float radius = KAPPA / sqrtf(*rho2);
    float w0 = W[r * 128 + t];
    float a = fabsf(w0);
    sa[t] = a;
    __syncthreads();
    int rank = 0;
    #pragma unroll 8
    for (int j = 0; j < 128; ++j) {
        float aj = sa[j];
        rank += (aj > a) || (aj == a && j < t);
    }
    ssort[rank] = a;
    __syncthreads();
    sc[t] = ssort[t];
    __syncthreads();
    for (int off = 1; off < 128; off <<= 1) {
        float add = (t >= off) ? sc[t - off] : 0.f;
        __syncthreads();
        sc[t] += add;
        __syncthreads();
    }
    bool flag = ssort[t] * (float)(t + 1) > sc[t] - radius;
    unsigned long long b = __ballot(flag);
    if ((t & 63) == 0) cnt2[t >> 6] = __popcll(b);
    __syncthreads();
    int rho = cnt2[0] + cnt2[1];
    float total = sc[127];
    bool needs = total > radius;
    float theta = (sc[rho - 1] - radius) / (float)rho;
    float o;
    if (needs) {
        float am = a - theta;
        o = (am > 0.f) ? ((w0 > 0.f) ? am : -am) : 0.f;
    } else o = w0;
    Wp[r * 128 + t] = o;
    WpT[t * 128 + r] = o;
}

// ---------------- CSR builds (by src AND by dst) ----------------

__global__ void count_deg_both(const int* __restrict__ src, const int* __restrict__ dst,
                               int* deg_s, int* deg_d, int E) {
    int e = blockIdx.x * blockDim.x + threadIdx.x;
    if (e < E) {
        atomicAdd(&deg_s[src[e]], 1);
        atomicAdd(&deg_d[dst[e]], 1);
    }
}

__global__ __launch_bounds__(1024) void scan_offsets(const int* __restrict__ deg,
                                                     int* offsets, int* cursor, int n) {
    __shared__ int partial[1024];
    int tid = threadIdx.x;
    int chunk = (n + 1023) / 1024;
    int lo = tid * chunk;
    int hi = lo + chunk; if (hi > n) hi = n; if (lo > n) lo = n;
    int s = 0;
    for (int i = lo; i < hi; ++i) s += deg[i];
    partial[tid] = s;
    __syncthreads();
    for (int od = 1; od < 1024; od <<= 1) {
        int val = 0;
        if (tid >= od) val = partial[tid - od];
        __syncthreads();
        if (tid >= od) partial[tid] += val;
        __syncthreads();
    }
    int base = (tid == 0) ? 0 : partial[tid - 1];
    for (int i = lo; i < hi; ++i) {
        offsets[i] = base; cursor[i] = base;
        base += deg[i];
    }
    if (tid == 1023) offsets[n] = partial[1023];
}

__global__ void fill_csr_both(const int* __restrict__ src, const int* __restrict__ dst,
                              const float* __restrict__ w,
                              int* cur_s, int* csr_dst, float* csr_ws,
                              int* cur_d, int* csr_src, float* csr_wd, int E) {
    int e = blockIdx.x * blockDim.x + threadIdx.x;
    if (e < E) {
        int s = src[e], d = dst[e];
        float ww = w[e];
        int ps = atomicAdd(&cur_s[s], 1);
        csr_dst[ps] = d;
        csr_ws[ps] = ww;
        int pd = atomicAdd(&cur_d[d], 1);
        csr_src[pd] = s;
        csr_wd[pd] = ww;
    }
}

// ---------------- small transposes ----------------

__global__ void transpose_om(const float* __restrict__ Om, float* OmT) {
    int idx = blockIdx.x * blockDim.x + threadIdx.x;
    if (idx < 128 * 256) {
        int t = idx / 256, k = idx % 256;
        OmT[k * 128 + t] = Om[idx];
    }
}

__global__ void transpose_x0(const float* __restrict__ X0, float* Xt, int n) {
    __shared__ float tile[32][33];
    int jb = blockIdx.x * 32, tb = blockIdx.y * 32;
    int tx = threadIdx.x, ty = threadIdx.y;
    for (int r = 0; r < 32; r += 8) {
        int t = tb + ty + r, j = jb + tx;
        tile[ty + r][tx] = (j < n) ? X0[(size_t)t * n + j] : 0.f;
    }
    __syncthreads();
    for (int r = 0; r < 32; r += 8) {
        int j = jb + ty + r, t = tb + tx;
        if (j < n) Xt[(size_t)j * 128 + t] = tile[tx][ty + r];
    }
}

// ---------------- one-shot dense GEMM: Ut = F^T @ OmT ----------------

__global__ __launch_bounds__(256) void gemm_u(const float* __restrict__ F,
                                              const float* __restrict__ OmT,
                                              float* __restrict__ C, int n) {
    __shared__ float Fs[16][129];
    __shared__ float Bs[16][129];
    int j0 = blockIdx.x * 128;
    int tid = threadIdx.x;
    int tj = tid >> 4, tg = tid & 15;
    float acc[8][8] = {};
    for (int k0 = 0; k0 < 256; k0 += 16) {
        for (int r = 0; r < 8; ++r) {
            int idx = r * 256 + tid;
            int kk = idx >> 7, jj = idx & 127;
            int j = j0 + jj;
            Fs[kk][jj] = (j < n) ? F[(size_t)(k0 + kk) * n + j] : 0.f;
            Bs[kk][jj] = OmT[(k0 + kk) * 128 + jj];
        }
        __syncthreads();
        for (int kk = 0; kk < 16; ++kk) {
            float a[8], b[8];
            #pragma unroll
            for (int u = 0; u < 8; ++u) a[u] = Fs[kk][tj + 16 * u];
            #pragma unroll
            for (int u = 0; u < 8; ++u) b[u] = Bs[kk][tg + 16 * u];
            #pragma unroll
            for (int x = 0; x < 8; ++x)
                #pragma unroll
                for (int y = 0; y < 8; ++y)
                    acc[x][y] += a[x] * b[y];
        }
        __syncthreads();
    }
    for (int x = 0; x < 8; ++x) {
        int j = j0 + tj + 16 * x;
        if (j < n)
            for (int y = 0; y < 8; ++y)
                C[(size_t)j * 128 + tg + 16 * y] = acc[x][y];
    }
}

// ---------------- spmm: wave-per-node gather, 8-wide index preload ----------------

__global__ __launch_bounds__(256) void spmm_csr(const int* __restrict__ offsets,
                                                const int* __restrict__ csr_src,
                                                const float* __restrict__ csr_w,
                                                const float* __restrict__ Xin,
                                                float* __restrict__ Yout, int n) {
    int j = blockIdx.x * 4 + (threadIdx.x >> 6);
    if (j >= n) return;
    int lane = threadIdx.x & 63;
    int lo = offsets[j], hi = offsets[j + 1];
    const float2* __restrict__ X2 = (const float2*)Xin;
    float2 acc = {0.f, 0.f};
    int e = lo;
    for (; e + 8 <= hi; e += 8) {
        int s[8]; float w[8];
        #pragma unroll
        for (int u = 0; u < 8; ++u) { s[u] = csr_src[e + u]; w[u] = csr_w[e + u]; }
        float2 x[8];
        #pragma unroll
        for (int u = 0; u < 8; ++u) x[u] = X2[(size_t)s[u] * 64 + lane];
        #pragma unroll
        for (int u = 0; u < 8; ++u) {
            acc.x += w[u] * x[u].x;
            acc.y += w[u] * x[u].y;
        }
    }
    for (; e < hi; ++e) {
        int s = csr_src[e];
        float w = csr_w[e];
        float2 x = X2[(size_t)s * 64 + lane];
        acc.x += w * x.x;
        acc.y += w * x.y;
    }
    ((float2*)Yout)[(size_t)j * 64 + lane] = acc;
}

// ---------------- gemm_relu: Xt = relu(Yt @ WpT + bt) ----------------

__global__ __launch_bounds__(256) void gemm_relu(const float* __restrict__ Yt,
                                                 const float* __restrict__ WpT,
                                                 const float* __restrict__ bt,
                                                 float* __restrict__ Xt, int n) {
    __shared__ float As[16][129];
    __shared__ float Bs[16][129];
    int j0 = blockIdx.x * 128;
    int tid = threadIdx.x;
    int tj = tid >> 4, tg = tid & 15;
    float acc[8][8] = {};
    for (int k0 = 0; k0 < 128; k0 += 16) {
        for (int r = 0; r < 8; ++r) {
            int idx = r * 256 + tid;
            {
                int jj = idx >> 4, kk = idx & 15;
                int j = j0 + jj;
                As[kk][jj] = (j < n) ? Yt[(size_t)j * 128 + k0 + kk] : 0.f;
            }
            {
                int kk = idx >> 7, tt = idx & 127;
                Bs[kk][tt] = WpT[(k0 + kk) * 128 + tt];
            }
        }
        __syncthreads();
        for (int kk = 0; kk < 16; ++kk) {
            float a[8], b[8];
            #pragma unroll
            for (int u = 0; u < 8; ++u) a[u] = As[kk][tj + 16 * u];
            #pragma unroll
            for (int u = 0; u < 8; ++u) b[u] = Bs[kk][tg + 16 * u];
            #pragma unroll
            for (int x = 0; x < 8; ++x)
                #pragma unroll
                for (int y = 0; y < 8; ++y)
                    acc[x][y] += a[x] * b[y];
        }
        __syncthreads();
    }
    for (int x = 0; x < 8; ++x) {
        int j = j0 + tj + 16 * x;
        if (j < n)
            for (int y = 0; y < 8; ++y) {
                int c = tg + 16 * y;
                float v = acc[x][y] + bt[(size_t)j * 128 + c];
                Xt[(size_t)j * 128 + c] = (v > 0.f) ? v : 0.f;
            }
    }
}

// ---------------- final: normalize rows + H @ Vw^T ----------------

__global__ __launch_bounds__(256) void final_out(const float* __restrict__ Xt,
                                                 const float* __restrict__ Vw,
                                                 float* __restrict__ out, int n) {
    __shared__ float Vs[40][132];
    int tid = threadIdx.x;
    int jb = blockIdx.x * 64;
    for (int i = tid; i < 40 * 128; i += 256) {
        int c = i >> 7, k = i & 127;
        Vs[c][(k >> 5) * 33 + (k & 31)] = Vw[i];
    }
    int g = tid >> 2, q = tid & 3;
    int j = jb + g;
    float4 xv[8];
    float ss = 0.f;
    if (j < n) {
        const float4* X4 = (const float4*)(Xt + (size_t)j * 128 + q * 32);
        #pragma unroll
        for (int u = 0; u < 8; ++u) {
            xv[u] = X4[u];
            ss += xv[u].x * xv[u].x + xv[u].y * xv[u].y
                + xv[u].z * xv[u].z + xv[u].w * xv[u].w;
        }
    } else {
        #pragma unroll
        for (int u = 0; u < 8; ++u) xv[u] = make_float4(0.f, 0.f, 0.f, 0.f);
    }
    ss += __shfl_xor(ss, 1, 64);
    ss += __shfl_xor(ss, 2, 64);
    float inv = 1.f / fmaxf(sqrtf(ss), 1e-12f);
    #pragma unroll
    for (int u = 0; u < 8; ++u) {
        xv[u].x *= inv; xv[u].y *= inv; xv[u].z *= inv; xv[u].w *= inv;
    }
    __syncthreads();
    float pacc[10];
    #pragma unroll
    for (int cc = 0; cc < 10; ++cc) pacc[cc] = 0.f;
    #pragma unroll 1
    for (int c = 0; c < 40; ++c) {
        const float* vrow = &Vs[c][q * 33];
        float acc = 0.f;
        #pragma unroll
        for (int u = 0; u < 8; ++u) {
            acc += xv[u].x * vrow[4 * u]     + xv[u].y * vrow[4 * u + 1]
                 + xv[u].z * vrow[4 * u + 2] + xv[u].w * vrow[4 * u + 3];
        }
        acc += __shfl_xor(acc, 1, 64);
        acc += __shfl_xor(acc, 2, 64);
        if ((c & 3) == q) pacc[c >> 2] = acc;
    }
    if (j < n) {
        #pragma unroll
        for (int cc = 0; cc < 10; ++cc) {
            int c = cc * 4 + q;
            out[(size_t)j * 40 + c] = pacc[cc];
        }
    }
}

// ---------------- launch ----------------

extern "C" void kernel_launch(void* const* d_in, const int* in_sizes, int n_in,
                              void* d_out, int out_size, void* d_ws, size_t ws_size,
                              hipStream_t stream) {
    const float* F    = (const float*)d_in[0];   // (256, 50000)
    const float* W    = (const float*)d_in[1];   // (128, 128)
    const float* Om   = (const float*)d_in[2];   // (128, 256)
    const float* Vw   = (const float*)d_in[3];   // (40, 128)
    const float* X0   = (const float*)d_in[4];   // (128, 50000)
    const float* ew   = (const float*)d_in[5];   // (E,)
    const int*   esrc = (const int*)d_in[6];
    const int*   edst = (const int*)d_in[7];
    float* out = (float*)d_out;
    (void)in_sizes; (void)n_in; (void)out_size; (void)ws_size;

    char* ws = (char*)d_ws;
    size_t off = 0;
    auto alloc = [&](size_t bytes) -> void* {
        void* p = ws + off;
        off = (off + bytes + 255) & ~(size_t)255;
        return p;
    };
    float* buf0    = (float*)alloc((size_t)N_NODES * 4);
    float* buf1    = (float*)alloc((size_t)N_NODES * 4);
    float* ss      = (float*)alloc(64 * 4);
    int*   deg2    = (int*)  alloc((size_t)2 * (N_NODES + 1) * 4);  // [src | dst]
    int*   offs_s  = (int*)  alloc((size_t)(N_NODES + 1) * 4);
    int*   offs_d  = (int*)  alloc((size_t)(N_NODES + 1) * 4);
    int*   cur_s   = (int*)  alloc((size_t)N_NODES * 4);
    int*   cur_d   = (int*)  alloc((size_t)N_NODES * 4);
    int*   csr_dst = (int*)  alloc((size_t)N_EDGES * 4);   // by-src CSR: dst indices
    float* csr_ws  = (float*)alloc((size_t)N_EDGES * 4);
    int*   csr_src = (int*)  alloc((size_t)N_EDGES * 4);   // by-dst CSR: src indices
    float* csr_wd  = (float*)alloc((size_t)N_EDGES * 4);
    float* Wp      = (float*)alloc(128 * 128 * 4);
    float* WpT     = (float*)alloc(128 * 128 * 4);
    float* OmT     = (float*)alloc(256 * 128 * 4);
    float* bt      = (float*)alloc((size_t)N_NODES * 128 * 4);
    float* Ut      = (float*)alloc((size_t)N_NODES * 128 * 4);
    float* Xa      = (float*)alloc((size_t)N_NODES * 128 * 4);
    float* Xb      = (float*)alloc((size_t)N_NODES * 128 * 4);

    int* deg_s = deg2;
    int* deg_d = deg2 + (N_NODES + 1);

    hipMemsetAsync(deg2, 0, (size_t)2 * (N_NODES + 1) * 4, stream);

    // ---- CSR builds (both directions) ----
    count_deg_both<<<(N_EDGES + 255) / 256, 256, 0, stream>>>(esrc, edst, deg_s, deg_d, N_EDGES);
    scan_offsets<<<1, 1024, 0, stream>>>(deg_s, offs_s, cur_s, N_NODES);
    scan_offsets<<<1, 1024, 0, stream>>>(deg_d, offs_d, cur_d, N_NODES);
    fill_csr_both<<<(N_EDGES + 255) / 256, 256, 0, stream>>>(
        esrc, edst, ew, cur_s, csr_dst, csr_ws, cur_d, csr_src, csr_wd, N_EDGES);

    // ---- power iteration: 1 gather-matvec kernel per step ----
    fill_pow<<<(N_NODES + 255) / 256, 256, 0, stream>>>(
        buf0, ss, N_NODES, 1.f / sqrtf((float)N_NODES));
    float* bufs[2] = {buf0, buf1};
    for (int it = 0; it <= PWR_ITERS; ++it) {
        matvec_norm<<<(N_NODES + 255) / 256, 256, 0, stream>>>(
            offs_s, csr_dst, csr_ws, bufs[it & 1], ss + it,
            bufs[(it + 1) & 1], ss + it + 1, N_NODES);
    }

    // ---- project W (rho^2 = ss[PWR_ITERS+1]) ----
    project_w<<<128, 128, 0, stream>>>(W, ss + PWR_ITERS + 1, Wp, WpT);

    // ---- b = (Omega_1 @ U) @ A ----
    transpose_om<<<(128 * 256 + 255) / 256, 256, 0, stream>>>(Om, OmT);
    gemm_u<<<(N_NODES + 127) / 128, 256, 0, stream>>>(F, OmT, Ut, N_NODES);
    spmm_csr<<<(N_NODES + 3) / 4, 256, 0, stream>>>(offs_d, csr_src, csr_wd, Ut, bt, N_NODES);

    // ---- fixed point ----
    transpose_x0<<<dim3((N_NODES + 31) / 32, 4), dim3(32, 8), 0, stream>>>(X0, Xa, N_NODES);
    float* xb2[2] = {Xa, Xb};
    for (int it = 0; it < FP_ITERS; ++it) {
        spmm_csr<<<(N_NODES + 3) / 4, 256, 0, stream>>>(
            offs_d, csr_src, csr_wd, xb2[it & 1], Ut, N_NODES);   // Ut reused as Y scratch
        gemm_relu<<<(N_NODES + 127) / 128, 256, 0, stream>>>(
            Ut, WpT, bt, xb2[(it + 1) & 1], N_NODES);
    }

    // ---- output ----
    final_out<<<(N_NODES + 63) / 64, 256, 0, stream>>>(xb2[FP_ITERS & 1], Vw, out, N_NODES);
}